// Round 1
// baseline (294.381 us; speedup 1.0000x reference)
//
#include <hip/hip_runtime.h>
#include <hip/hip_bf16.h>
#include <stdint.h>

#define EMBED 128
#define HID 145
#define HPAD 152            // padded per-table column count (bf16), row = 304 B (19 x 16 B)
#define NPROJ 304           // 2 * HPAD  (u half + v half)
#define WPS 320             // packed-W row stride in floats (cols 304..319 are zero)

__device__ __forceinline__ float bf2f(uint16_t b) {
    return __uint_as_float(((uint32_t)b) << 16);
}
__device__ __forceinline__ uint16_t f2bf(float f) {
    uint32_t x = __float_as_uint(f);
    x += 0x7FFFu + ((x >> 16) & 1u);          // round-to-nearest-even
    return (uint16_t)(x >> 16);
}

// ---------------------------------------------------------------------------
// prep_small: detect edge_index dtype, fold cancer/causal columns into vectors
// ---------------------------------------------------------------------------
__global__ void __launch_bounds__(256)
prep_small(const float* __restrict__ cancer, const float* __restrict__ W1,
           const float* __restrict__ b1, const float* __restrict__ W2,
           const void* __restrict__ eiv,
           int* __restrict__ flag, float* __restrict__ b1p, float* __restrict__ wci,
           float* __restrict__ wcj, float* __restrict__ w2p)
{
    const int t = threadIdx.x;
    if (t == 0) {
        // int64 indices < 50000 => every odd 32-bit word is zero.
        const uint32_t* p = (const uint32_t*)eiv;
        uint32_t o = p[1] | p[3] | p[5] | p[7] | p[9] | p[11] | p[13] | p[15];
        *flag = (o == 0u) ? 1 : 0;
    }
    if (t < HPAD) {
        float bv = 0.f, a = 0.f, b = 0.f, w2 = 0.f;
        if (t < HID) {
            float s = b1[t];
            #pragma unroll
            for (int k = 0; k < 32; ++k)
                s = fmaf(cancer[k], W1[(size_t)(2 * EMBED + k) * HID + t], s);
            bv = s;
            a  = W1[(size_t)288 * HID + t] + W1[(size_t)290 * HID + t];  // c_i + diff
            b  = W1[(size_t)289 * HID + t] - W1[(size_t)290 * HID + t];  // c_j - diff
            w2 = W2[t];
        }
        b1p[t] = bv; wci[t] = a; wcj[t] = b; w2p[t] = w2;
    }
}

// ---------------------------------------------------------------------------
// prep_pack: pack W1's A|B halves into Wp[128][WPS], zero-padded columns
// ---------------------------------------------------------------------------
__global__ void __launch_bounds__(256)
prep_pack(const float* __restrict__ W1, float* __restrict__ Wp)
{
    const int idx = blockIdx.x * 256 + threadIdx.x;     // < 128*WPS
    const int k = idx / WPS, j = idx % WPS;
    float val = 0.f;
    if (j < HID)                         val = W1[(size_t)k * HID + j];
    else if (j >= HPAD && j < HPAD + HID) val = W1[(size_t)(EMBED + k) * HID + (j - HPAD)];
    Wp[idx] = val;
}

// ---------------------------------------------------------------------------
// proj_kernel: u[n] = h[n] @ A, v[n] = h[n] @ B, stored bf16, HPAD columns
//   block: 256 threads, 32 nodes. thread = (jt = t&63 column lane, mg = t>>6)
//   each thread: 8 nodes x 5 columns register tile (W reused across 8 nodes)
// ---------------------------------------------------------------------------
__global__ void __launch_bounds__(256)
proj_kernel(const float* __restrict__ h, const float* __restrict__ Wp,
            uint16_t* __restrict__ u, uint16_t* __restrict__ v, int nNodes)
{
    __shared__ float hs[32 * EMBED];
    const int t = threadIdx.x;
    const int n0 = blockIdx.x * 32;
    const long total = (long)nNodes * EMBED;

    if ((long)(n0 + 32) * EMBED <= total) {
        const float4* src4 = (const float4*)(h + (size_t)n0 * EMBED);
        #pragma unroll
        for (int r = 0; r < 4; ++r)
            ((float4*)hs)[t + 256 * r] = src4[t + 256 * r];
    } else {
        for (int r = 0; r < 16; ++r) {
            int e = t + 256 * r;
            long g = (long)n0 * EMBED + e;
            hs[e] = (g < total) ? h[g] : 0.f;
        }
    }
    __syncthreads();

    const int jt = t & 63;
    const int mg = t >> 6;

    float acc[8][5];
    #pragma unroll
    for (int a = 0; a < 8; ++a)
        #pragma unroll
        for (int b = 0; b < 5; ++b) acc[a][b] = 0.f;

    for (int k4 = 0; k4 < EMBED / 4; ++k4) {
        float4 hk[8];
        #pragma unroll
        for (int mm = 0; mm < 8; ++mm)
            hk[mm] = *(const float4*)(hs + (mg + 4 * mm) * EMBED + 4 * k4);
        #pragma unroll
        for (int kk = 0; kk < 4; ++kk) {
            float w[5];
            #pragma unroll
            for (int i = 0; i < 5; ++i)
                w[i] = Wp[(size_t)(4 * k4 + kk) * WPS + jt + 64 * i];
            #pragma unroll
            for (int mm = 0; mm < 8; ++mm) {
                const float hv = (&hk[mm].x)[kk];
                #pragma unroll
                for (int i = 0; i < 5; ++i)
                    acc[mm][i] = fmaf(hv, w[i], acc[mm][i]);
            }
        }
    }

    #pragma unroll
    for (int i = 0; i < 5; ++i) {
        const int j = jt + 64 * i;
        if (j < NPROJ) {
            uint16_t* base = (j < HPAD) ? u : v;
            const int col  = (j < HPAD) ? j : j - HPAD;
            #pragma unroll
            for (int mm = 0; mm < 8; ++mm) {
                const int n = n0 + mg + 4 * mm;
                if (n < nNodes) base[(size_t)n * HPAD + col] = f2bf(acc[mm][i]);
            }
        }
    }
}

// ---------------------------------------------------------------------------
// edge_kernel: one wave per edge (grid-stride). 19 lanes x float4 gather rows.
// ---------------------------------------------------------------------------
__global__ void __launch_bounds__(256)
edge_kernel(const void* __restrict__ eiv, const float* __restrict__ causal,
            const uint16_t* __restrict__ u, const uint16_t* __restrict__ v,
            const float* __restrict__ b1p, const float* __restrict__ wci,
            const float* __restrict__ wcj, const float* __restrict__ w2p,
            const float* __restrict__ b2, const int* __restrict__ flag,
            float* __restrict__ out, int E)
{
    const int lane = threadIdx.x & 63;
    const int wpb  = blockDim.x >> 6;
    const int wid  = blockIdx.x * wpb + (threadIdx.x >> 6);
    const int nW   = gridDim.x * wpb;
    const int is64 = *flag;
    const float bias2 = *b2;

    float B1[8], CI[8], CJ[8], W2r[8];
    #pragma unroll
    for (int m = 0; m < 8; ++m) { B1[m] = 0.f; CI[m] = 0.f; CJ[m] = 0.f; W2r[m] = 0.f; }
    if (lane < 19) {
        #pragma unroll
        for (int m = 0; m < 8; ++m) {
            B1[m]  = b1p[lane * 8 + m];
            CI[m]  = wci[lane * 8 + m];
            CJ[m]  = wcj[lane * 8 + m];
            W2r[m] = w2p[lane * 8 + m];
        }
    }

    const long long* e64 = (const long long*)eiv;
    const int*       e32 = (const int*)eiv;

    for (int e = wid; e < E; e += nW) {
        int src, dst;
        if (is64) { src = (int)e64[e]; dst = (int)e64[(size_t)E + e]; }
        else      { src = e32[e];      dst = e32[(size_t)E + e]; }
        const float ci = causal[src];
        const float cj = causal[dst];

        float partial = 0.f;
        if (lane < 19) {
            uint4 ur = *(const uint4*)(u + (size_t)src * HPAD + lane * 8);
            uint4 vr = *(const uint4*)(v + (size_t)dst * HPAD + lane * 8);
            const uint16_t* uu = (const uint16_t*)&ur;
            const uint16_t* vv = (const uint16_t*)&vr;
            #pragma unroll
            for (int m = 0; m < 8; ++m) {
                float tv = bf2f(uu[m]) + bf2f(vv[m])
                         + fmaf(ci, CI[m], fmaf(cj, CJ[m], B1[m]));
                tv = fmaxf(tv, 0.f);
                partial = fmaf(tv, W2r[m], partial);
            }
        }
        #pragma unroll
        for (int m = 32; m; m >>= 1) partial += __shfl_xor(partial, m, 64);
        if (lane == 0) out[e] = 1.f / (1.f + __expf(-(partial + bias2)));
    }
}

// ---------------------------------------------------------------------------
// fallback_kernel: direct per-edge compute (only if workspace too small)
// ---------------------------------------------------------------------------
__global__ void __launch_bounds__(256)
fallback_kernel(const void* __restrict__ eiv, const float* __restrict__ h,
                const float* __restrict__ cancer, const float* __restrict__ causal,
                const float* __restrict__ W1, const float* __restrict__ b1,
                const float* __restrict__ W2, const float* __restrict__ b2,
                float* __restrict__ out, int E)
{
    const int lane = threadIdx.x & 63;
    const int wpb  = blockDim.x >> 6;
    const int wid  = blockIdx.x * wpb + (threadIdx.x >> 6);
    const int nW   = gridDim.x * wpb;
    const uint32_t* p32 = (const uint32_t*)eiv;
    const uint32_t o = p32[1] | p32[3] | p32[5] | p32[7] | p32[9] | p32[11] | p32[13] | p32[15];
    const int is64 = (o == 0u);
    const long long* e64 = (const long long*)eiv;
    const int*       e32 = (const int*)eiv;
    const float bias2 = *b2;

    for (int e = wid; e < E; e += nW) {
        int src, dst;
        if (is64) { src = (int)e64[e]; dst = (int)e64[(size_t)E + e]; }
        else      { src = e32[e];      dst = e32[(size_t)E + e]; }
        const float ci = causal[src], cj = causal[dst];
        float acc0 = 0.f, acc1 = 0.f, acc2 = 0.f;
        const int j0 = lane, j1 = lane + 64, j2 = lane + 128;
        for (int k = 0; k < 291; ++k) {
            float f;
            if      (k < 128) f = h[(size_t)src * 128 + k];
            else if (k < 256) f = h[(size_t)dst * 128 + (k - 128)];
            else if (k < 288) f = cancer[k - 256];
            else if (k == 288) f = ci;
            else if (k == 289) f = cj;
            else               f = ci - cj;
            const float* wr = W1 + (size_t)k * HID;
            acc0 = fmaf(f, wr[j0], acc0);
            acc1 = fmaf(f, wr[j1], acc1);
            if (j2 < HID) acc2 = fmaf(f, wr[j2], acc2);
        }
        float partial = fmaxf(acc0 + b1[j0], 0.f) * W2[j0]
                      + fmaxf(acc1 + b1[j1], 0.f) * W2[j1];
        if (j2 < HID) partial += fmaxf(acc2 + b1[j2], 0.f) * W2[j2];
        #pragma unroll
        for (int m = 32; m; m >>= 1) partial += __shfl_xor(partial, m, 64);
        if (lane == 0) out[e] = 1.f / (1.f + __expf(-(partial + bias2)));
    }
}

// ---------------------------------------------------------------------------
extern "C" void kernel_launch(void* const* d_in, const int* in_sizes, int n_in,
                              void* d_out, int out_size, void* d_ws, size_t ws_size,
                              hipStream_t stream)
{
    const float* h      = (const float*)d_in[0];
    const void*  ei     = d_in[1];
    const float* cancer = (const float*)d_in[2];
    const float* causal = (const float*)d_in[3];
    const float* W1     = (const float*)d_in[4];
    const float* b1     = (const float*)d_in[5];
    const float* W2     = (const float*)d_in[6];
    const float* b2     = (const float*)d_in[7];
    float* outp = (float*)d_out;

    const int nNodes = in_sizes[0] / EMBED;
    const int E      = in_sizes[1] / 2;

    const size_t U_OFF   = 262144;                                  // Wp ends at 172032
    const size_t tabB    = (size_t)nNodes * HPAD * sizeof(uint16_t);
    const size_t V_OFF   = (U_OFF + tabB + 255) & ~(size_t)255;
    const size_t need    = V_OFF + tabB;

    if (ws_size >= need) {
        char* ws = (char*)d_ws;
        int*      flag = (int*)ws;
        float*    b1p  = (float*)(ws + 1024);
        float*    wci  = (float*)(ws + 2048);
        float*    wcj  = (float*)(ws + 3072);
        float*    w2p  = (float*)(ws + 4096);
        float*    Wp   = (float*)(ws + 8192);
        uint16_t* u    = (uint16_t*)(ws + U_OFF);
        uint16_t* v    = (uint16_t*)(ws + V_OFF);

        prep_small<<<1, 256, 0, stream>>>(cancer, W1, b1, W2, ei, flag, b1p, wci, wcj, w2p);
        prep_pack<<<(EMBED * WPS) / 256, 256, 0, stream>>>(W1, Wp);
        proj_kernel<<<(nNodes + 31) / 32, 256, 0, stream>>>(h, Wp, u, v, nNodes);
        edge_kernel<<<2048, 256, 0, stream>>>(ei, causal, u, v, b1p, wci, wcj, w2p,
                                              b2, flag, outp, E);
    } else {
        fallback_kernel<<<2048, 256, 0, stream>>>(ei, h, cancer, causal, W1, b1, W2, b2,
                                                  outp, E);
    }
}

// Round 2
// 171.982 us; speedup vs baseline: 1.7117x; 1.7117x over previous
//
#include <hip/hip_runtime.h>
#include <hip/hip_bf16.h>
#include <stdint.h>

#define EMBED 128
#define HID 145
#define HSTR 160            // per-table padded columns; row = 320 B = 5 x 64 B lines
#define WPS 320             // packed-W row stride in floats: A -> cols 0..144, B -> cols 160..304

__device__ __forceinline__ float bf2f(uint16_t b) {
    return __uint_as_float(((uint32_t)b) << 16);
}
__device__ __forceinline__ uint16_t f2bf(float f) {
    uint32_t x = __float_as_uint(f);
    x += 0x7FFFu + ((x >> 16) & 1u);          // round-to-nearest-even
    return (uint16_t)(x >> 16);
}

// ---------------------------------------------------------------------------
// prep_small: detect edge_index dtype; fold cancer-block + b1 into b1p,
// causal columns into wci/wcj; copy W2 zero-padded to 160.
// ---------------------------------------------------------------------------
__global__ void __launch_bounds__(256)
prep_small(const float* __restrict__ cancer, const float* __restrict__ W1,
           const float* __restrict__ b1, const float* __restrict__ W2,
           const void* __restrict__ eiv,
           int* __restrict__ flag, float* __restrict__ b1p, float* __restrict__ wci,
           float* __restrict__ wcj, float* __restrict__ w2p)
{
    const int t = threadIdx.x;
    if (t == 0) {
        // int64 indices < 50000 => every odd 32-bit word is zero.
        const uint32_t* p = (const uint32_t*)eiv;
        uint32_t o = p[1] | p[3] | p[5] | p[7] | p[9] | p[11] | p[13] | p[15];
        *flag = (o == 0u) ? 1 : 0;
    }
    if (t < HSTR) {
        float bv = 0.f, a = 0.f, b = 0.f, w2 = 0.f;
        if (t < HID) {
            float s = b1[t];
            #pragma unroll
            for (int k = 0; k < 32; ++k)
                s = fmaf(cancer[k], W1[(size_t)(2 * EMBED + k) * HID + t], s);
            bv = s;
            a  = W1[(size_t)288 * HID + t] + W1[(size_t)290 * HID + t];  // c_i + diff
            b  = W1[(size_t)289 * HID + t] - W1[(size_t)290 * HID + t];  // c_j - diff
            w2 = W2[t];
        }
        b1p[t] = bv; wci[t] = a; wcj[t] = b; w2p[t] = w2;
    }
}

// ---------------------------------------------------------------------------
// prep_pack: pack W1's A|B halves into Wp[128][WPS], zero-padded columns
// ---------------------------------------------------------------------------
__global__ void __launch_bounds__(256)
prep_pack(const float* __restrict__ W1, float* __restrict__ Wp)
{
    const int idx = blockIdx.x * 256 + threadIdx.x;     // < 128*WPS
    const int k = idx / WPS, j = idx % WPS;
    float val = 0.f;
    if (j < HID)                              val = W1[(size_t)k * HID + j];
    else if (j >= HSTR && j < HSTR + HID)     val = W1[(size_t)(EMBED + k) * HID + (j - HSTR)];
    Wp[idx] = val;
}

// ---------------------------------------------------------------------------
// proj_kernel: u'[n] = h[n]@A + b1p + causal[n]*wci   (bf16, HSTR cols)
//              v'[n] = h[n]@B        + causal[n]*wcj
//   block: 256 threads, 32 nodes. thread = (jt = t&63 column lane, mg = t>>6)
//   each thread: 8 nodes x 5 columns register tile (W reused across 8 nodes)
// ---------------------------------------------------------------------------
__global__ void __launch_bounds__(256)
proj_kernel(const float* __restrict__ h, const float* __restrict__ Wp,
            const float* __restrict__ causal, const float* __restrict__ b1p,
            const float* __restrict__ wci, const float* __restrict__ wcj,
            uint16_t* __restrict__ u, uint16_t* __restrict__ v, int nNodes)
{
    __shared__ float hs[32 * EMBED];
    const int t = threadIdx.x;
    const int n0 = blockIdx.x * 32;
    const long total = (long)nNodes * EMBED;

    if ((long)(n0 + 32) * EMBED <= total) {
        const float4* src4 = (const float4*)(h + (size_t)n0 * EMBED);
        #pragma unroll
        for (int r = 0; r < 4; ++r)
            ((float4*)hs)[t + 256 * r] = src4[t + 256 * r];
    } else {
        for (int r = 0; r < 16; ++r) {
            int e = t + 256 * r;
            long g = (long)n0 * EMBED + e;
            hs[e] = (g < total) ? h[g] : 0.f;
        }
    }
    __syncthreads();

    const int jt = t & 63;
    const int mg = t >> 6;

    float acc[8][5];
    #pragma unroll
    for (int a = 0; a < 8; ++a)
        #pragma unroll
        for (int b = 0; b < 5; ++b) acc[a][b] = 0.f;

    for (int k4 = 0; k4 < EMBED / 4; ++k4) {
        float4 hk[8];
        #pragma unroll
        for (int mm = 0; mm < 8; ++mm)
            hk[mm] = *(const float4*)(hs + (mg + 4 * mm) * EMBED + 4 * k4);
        #pragma unroll
        for (int kk = 0; kk < 4; ++kk) {
            float w[5];
            #pragma unroll
            for (int i = 0; i < 5; ++i)
                w[i] = Wp[(size_t)(4 * k4 + kk) * WPS + jt + 64 * i];
            #pragma unroll
            for (int mm = 0; mm < 8; ++mm) {
                const float hv = (&hk[mm].x)[kk];
                #pragma unroll
                for (int i = 0; i < 5; ++i)
                    acc[mm][i] = fmaf(hv, w[i], acc[mm][i]);
            }
        }
    }

    float cz[8];
    #pragma unroll
    for (int mm = 0; mm < 8; ++mm) {
        const int n = n0 + mg + 4 * mm;
        cz[mm] = (n < nNodes) ? causal[n] : 0.f;
    }

    #pragma unroll
    for (int i = 0; i < 5; ++i) {
        const int j = jt + 64 * i;            // 0..319
        const bool isU = j < HSTR;
        const int col = isU ? j : j - HSTR;
        const float addB = isU ? b1p[col] : 0.f;
        const float addC = isU ? wci[col] : wcj[col];
        uint16_t* base = isU ? u : v;
        #pragma unroll
        for (int mm = 0; mm < 8; ++mm) {
            const int n = n0 + mg + 4 * mm;
            if (n < nNodes)
                base[(size_t)n * HSTR + col] = f2bf(acc[mm][i] + addB + cz[mm] * addC);
        }
    }
}

// ---------------------------------------------------------------------------
// edge_kernel: 4 lanes per edge, 16 edges per wave.
//   lane r of each group loads chunks {r, 4+r, 8+r, 12+r, 16+r} (16 B each)
//   of u'[src] and v'[dst]; per-lane W2 slice in registers; 2-shuffle reduce.
// ---------------------------------------------------------------------------
__global__ void __launch_bounds__(256)
edge_kernel(const void* __restrict__ eiv,
            const uint16_t* __restrict__ u, const uint16_t* __restrict__ v,
            const float* __restrict__ w2p, const float* __restrict__ b2,
            const int* __restrict__ flag, float* __restrict__ out, int E)
{
    const int t = threadIdx.x;
    const int lane = t & 63;
    const int r = lane & 3;                 // chunk lane within 4-lane group
    const int grp = lane >> 2;              // 0..15: edge group within wave
    const int wid = blockIdx.x * (blockDim.x >> 6) + (t >> 6);
    const int eg = wid * 16 + grp;
    const bool ok = eg < E;
    const int e = ok ? eg : 0;
    const int is64 = *flag;
    const float bias2 = *b2;

    // per-lane W2 slice: chunk c = 4i+r covers elems 8c..8c+7
    const float4* w2f4 = (const float4*)w2p;
    float4 W2a[5], W2b[5];
    #pragma unroll
    for (int i = 0; i < 5; ++i) {
        const int c = 4 * i + r;
        W2a[i] = w2f4[2 * c];
        W2b[i] = w2f4[2 * c + 1];
    }

    int src, dst;
    if (is64) {
        const long long* e64 = (const long long*)eiv;
        src = (int)e64[e]; dst = (int)e64[(size_t)E + e];
    } else {
        const int* e32 = (const int*)eiv;
        src = e32[e];     dst = e32[(size_t)E + e];
    }

    const char* ub = (const char*)u + (uint32_t)src * 320u + r * 16;
    const char* vb = (const char*)v + (uint32_t)dst * 320u + r * 16;
    uint4 U[5], V[5];
    #pragma unroll
    for (int i = 0; i < 5; ++i) U[i] = *(const uint4*)(ub + 64 * i);
    #pragma unroll
    for (int i = 0; i < 5; ++i) V[i] = *(const uint4*)(vb + 64 * i);

    float acc0 = 0.f, acc1 = 0.f;
    #pragma unroll
    for (int i = 0; i < 5; ++i) {
        const uint32_t* uw = (const uint32_t*)&U[i];
        const uint32_t* vw = (const uint32_t*)&V[i];
        const float* wA = (const float*)&W2a[i];
        const float* wB = (const float*)&W2b[i];
        #pragma unroll
        for (int p = 0; p < 4; ++p) {
            const float ulo = __uint_as_float(uw[p] << 16);
            const float uhi = __uint_as_float(uw[p] & 0xFFFF0000u);
            const float vlo = __uint_as_float(vw[p] << 16);
            const float vhi = __uint_as_float(vw[p] & 0xFFFF0000u);
            const float t0 = fmaxf(ulo + vlo, 0.f);
            const float t1 = fmaxf(uhi + vhi, 0.f);
            const float wp0 = (p < 2) ? wA[2 * p]     : wB[2 * (p - 2)];
            const float wp1 = (p < 2) ? wA[2 * p + 1] : wB[2 * (p - 2) + 1];
            acc0 = fmaf(t0, wp0, acc0);
            acc1 = fmaf(t1, wp1, acc1);
        }
    }
    float partial = acc0 + acc1;
    partial += __shfl_xor(partial, 1);
    partial += __shfl_xor(partial, 2);
    if (r == 0 && ok)
        out[e] = 1.f / (1.f + __expf(-(partial + bias2)));
}

// ---------------------------------------------------------------------------
// fallback_kernel: direct per-edge compute (only if workspace too small)
// ---------------------------------------------------------------------------
__global__ void __launch_bounds__(256)
fallback_kernel(const void* __restrict__ eiv, const float* __restrict__ h,
                const float* __restrict__ cancer, const float* __restrict__ causal,
                const float* __restrict__ W1, const float* __restrict__ b1,
                const float* __restrict__ W2, const float* __restrict__ b2,
                float* __restrict__ out, int E)
{
    const int lane = threadIdx.x & 63;
    const int wpb  = blockDim.x >> 6;
    const int wid  = blockIdx.x * wpb + (threadIdx.x >> 6);
    const int nW   = gridDim.x * wpb;
    const uint32_t* p32 = (const uint32_t*)eiv;
    const uint32_t o = p32[1] | p32[3] | p32[5] | p32[7] | p32[9] | p32[11] | p32[13] | p32[15];
    const int is64 = (o == 0u);
    const long long* e64 = (const long long*)eiv;
    const int*       e32 = (const int*)eiv;
    const float bias2 = *b2;

    for (int e = wid; e < E; e += nW) {
        int src, dst;
        if (is64) { src = (int)e64[e]; dst = (int)e64[(size_t)E + e]; }
        else      { src = e32[e];      dst = e32[(size_t)E + e]; }
        const float ci = causal[src], cj = causal[dst];
        float acc0 = 0.f, acc1 = 0.f, acc2 = 0.f;
        const int j0 = lane, j1 = lane + 64, j2 = lane + 128;
        for (int k = 0; k < 291; ++k) {
            float f;
            if      (k < 128) f = h[(size_t)src * 128 + k];
            else if (k < 256) f = h[(size_t)dst * 128 + (k - 128)];
            else if (k < 288) f = cancer[k - 256];
            else if (k == 288) f = ci;
            else if (k == 289) f = cj;
            else               f = ci - cj;
            const float* wr = W1 + (size_t)k * HID;
            acc0 = fmaf(f, wr[j0], acc0);
            acc1 = fmaf(f, wr[j1], acc1);
            if (j2 < HID) acc2 = fmaf(f, wr[j2], acc2);
        }
        float partial = fmaxf(acc0 + b1[j0], 0.f) * W2[j0]
                      + fmaxf(acc1 + b1[j1], 0.f) * W2[j1];
        if (j2 < HID) partial += fmaxf(acc2 + b1[j2], 0.f) * W2[j2];
        #pragma unroll
        for (int m = 32; m; m >>= 1) partial += __shfl_xor(partial, m, 64);
        if (lane == 0) out[e] = 1.f / (1.f + __expf(-(partial + bias2)));
    }
}

// ---------------------------------------------------------------------------
extern "C" void kernel_launch(void* const* d_in, const int* in_sizes, int n_in,
                              void* d_out, int out_size, void* d_ws, size_t ws_size,
                              hipStream_t stream)
{
    const float* h      = (const float*)d_in[0];
    const void*  ei     = d_in[1];
    const float* cancer = (const float*)d_in[2];
    const float* causal = (const float*)d_in[3];
    const float* W1     = (const float*)d_in[4];
    const float* b1     = (const float*)d_in[5];
    const float* W2     = (const float*)d_in[6];
    const float* b2     = (const float*)d_in[7];
    float* outp = (float*)d_out;

    const int nNodes = in_sizes[0] / EMBED;
    const int E      = in_sizes[1] / 2;

    const size_t U_OFF = 262144;                                   // Wp ends at 172032
    const size_t tabB  = (size_t)nNodes * HSTR * sizeof(uint16_t); // 16 MB
    const size_t V_OFF = (U_OFF + tabB + 255) & ~(size_t)255;
    const size_t need  = V_OFF + tabB;

    if (ws_size >= need) {
        char* ws = (char*)d_ws;
        int*      flag = (int*)ws;
        float*    b1p  = (float*)(ws + 1024);
        float*    wci  = (float*)(ws + 2048);
        float*    wcj  = (float*)(ws + 3072);
        float*    w2p  = (float*)(ws + 4096);
        float*    Wp   = (float*)(ws + 8192);
        uint16_t* u    = (uint16_t*)(ws + U_OFF);
        uint16_t* v    = (uint16_t*)(ws + V_OFF);

        prep_small<<<1, 256, 0, stream>>>(cancer, W1, b1, W2, ei, flag, b1p, wci, wcj, w2p);
        prep_pack<<<(EMBED * WPS) / 256, 256, 0, stream>>>(W1, Wp);
        proj_kernel<<<(nNodes + 31) / 32, 256, 0, stream>>>(h, Wp, causal, b1p, wci, wcj,
                                                            u, v, nNodes);
        const int waves  = (E + 15) / 16;
        const int blocks = (waves + 3) / 4;
        edge_kernel<<<blocks, 256, 0, stream>>>(ei, u, v, w2p, b2, flag, outp, E);
    } else {
        fallback_kernel<<<2048, 256, 0, stream>>>(ei, h, cancer, causal, W1, b1, W2, b2,
                                                  outp, E);
    }
}

// Round 3
// 133.174 us; speedup vs baseline: 2.2105x; 1.2914x over previous
//
#include <hip/hip_runtime.h>
#include <hip/hip_bf16.h>
#include <stdint.h>

#define EMBED 128
#define HID 145
#define HSTR 160            // per-table padded columns; row = 320 B = 5 x 64 B lines
#define NTILE 20            // 320 output cols / 16
#define KCH 4               // 128 K / 32

typedef __attribute__((ext_vector_type(8))) short short8;
typedef __attribute__((ext_vector_type(4))) float f32x4;

__device__ __forceinline__ uint16_t f2bf(float f) {
    uint32_t x = __float_as_uint(f);
    x += 0x7FFFu + ((x >> 16) & 1u);          // round-to-nearest-even
    return (uint16_t)(x >> 16);
}

// ---------------------------------------------------------------------------
// prep_small: detect edge_index dtype; fold cancer-block + b1 into b1p,
// causal columns into wci/wcj; copy W2 zero-padded to 160.
// ---------------------------------------------------------------------------
__global__ void __launch_bounds__(256)
prep_small(const float* __restrict__ cancer, const float* __restrict__ W1,
           const float* __restrict__ b1, const float* __restrict__ W2,
           const void* __restrict__ eiv,
           int* __restrict__ flag, float* __restrict__ b1p, float* __restrict__ wci,
           float* __restrict__ wcj, float* __restrict__ w2p)
{
    const int t = threadIdx.x;
    if (t == 0) {
        // int64 indices < 50000 => every odd 32-bit word is zero.
        const uint32_t* p = (const uint32_t*)eiv;
        uint32_t o = p[1] | p[3] | p[5] | p[7] | p[9] | p[11] | p[13] | p[15];
        *flag = (o == 0u) ? 1 : 0;
    }
    if (t < HSTR) {
        float bv = 0.f, a = 0.f, b = 0.f, w2 = 0.f;
        if (t < HID) {
            float s = b1[t];
            #pragma unroll
            for (int k = 0; k < 32; ++k)
                s = fmaf(cancer[k], W1[(size_t)(2 * EMBED + k) * HID + t], s);
            bv = s;
            a  = W1[(size_t)288 * HID + t] + W1[(size_t)290 * HID + t];  // c_i + diff
            b  = W1[(size_t)289 * HID + t] - W1[(size_t)290 * HID + t];  // c_j - diff
            w2 = W2[t];
        }
        b1p[t] = bv; wci[t] = a; wcj[t] = b; w2p[t] = w2;
    }
}

// ---------------------------------------------------------------------------
// prep_packb: pack W1's A|B halves into bf16 B-fragment order:
//   Wpb[ ((kc*20+tt)*64 + lane)*8 + reg ] = W[k][col],
//   k = kc*32 + (lane>>4)*8 + reg, col = tt*16 + (lane&15)
//   col 0..144 -> A half (W1 rows 0..127), col 160..304 -> B half (rows 128..255)
// ---------------------------------------------------------------------------
__global__ void __launch_bounds__(256)
prep_packb(const float* __restrict__ W1, short* __restrict__ Wpb)
{
    const int idx = blockIdx.x * 256 + threadIdx.x;   // < 40960
    const int reg  = idx & 7;
    const int lane = (idx >> 3) & 63;
    const int tl   = idx >> 9;                        // 0..79
    const int tt   = tl % NTILE;
    const int kc   = tl / NTILE;
    const int k    = kc * 32 + (lane >> 4) * 8 + reg;
    const int col  = tt * 16 + (lane & 15);
    float val = 0.f;
    if (col < HID)                                 val = W1[(size_t)k * HID + col];
    else if (col >= HSTR && col < HSTR + HID)      val = W1[(size_t)(EMBED + k) * HID + (col - HSTR)];
    Wpb[idx] = (short)f2bf(val);
}

// ---------------------------------------------------------------------------
// proj_mfma: u'[n] = h[n]@A + b1p + causal[n]*wci   (bf16, HSTR cols)
//            v'[n] = h[n]@B        + causal[n]*wcj
//   block = 4 waves = 64 nodes; wave computes 16 nodes x 320 cols via
//   20 tiles of mfma_f32_16x16x32_bf16 over 4 K-chunks.
//   A/B use the same k-slot mapping κ(hi,reg)=hi*8+reg (bijective => correct).
//   D layout (HW-verified): col = lane&15, row = (lane>>4)*4 + reg.
// ---------------------------------------------------------------------------
__global__ void __launch_bounds__(256)
proj_mfma(const float* __restrict__ h, const short* __restrict__ Wpb,
          const float* __restrict__ causal, const float* __restrict__ b1p,
          const float* __restrict__ wci, const float* __restrict__ wcj,
          uint16_t* __restrict__ u, uint16_t* __restrict__ v, int nNodes)
{
    const int t = threadIdx.x;
    const int lane = t & 63;
    const int w = t >> 6;
    const int lane15 = lane & 15, hi = lane >> 4;
    const int nbase = blockIdx.x * 64 + w * 16;

    int nodeA = nbase + lane15;
    if (nodeA >= nNodes) nodeA = nNodes - 1;
    const float* hrow = h + (size_t)nodeA * EMBED + hi * 8;

    short8 afr[KCH];
    #pragma unroll
    for (int kc = 0; kc < KCH; ++kc) {
        const float4 x = *(const float4*)(hrow + kc * 32);
        const float4 y = *(const float4*)(hrow + kc * 32 + 4);
        short8 a;
        a[0] = (short)f2bf(x.x); a[1] = (short)f2bf(x.y);
        a[2] = (short)f2bf(x.z); a[3] = (short)f2bf(x.w);
        a[4] = (short)f2bf(y.x); a[5] = (short)f2bf(y.y);
        a[6] = (short)f2bf(y.z); a[7] = (short)f2bf(y.w);
        afr[kc] = a;
    }

    f32x4 acc[NTILE];
    #pragma unroll
    for (int tt = 0; tt < NTILE; ++tt) acc[tt] = (f32x4){0.f, 0.f, 0.f, 0.f};

    const short8* bp = (const short8*)Wpb;
    #pragma unroll
    for (int kc = 0; kc < KCH; ++kc) {
        #pragma unroll
        for (int tt = 0; tt < NTILE; ++tt) {
            const short8 b = bp[(kc * NTILE + tt) * 64 + lane];
            acc[tt] = __builtin_amdgcn_mfma_f32_16x16x32_bf16(afr[kc], b, acc[tt], 0, 0, 0);
        }
    }

    float cz[4];
    #pragma unroll
    for (int j = 0; j < 4; ++j) {
        const int n = nbase + hi * 4 + j;
        cz[j] = (n < nNodes) ? causal[n] : 0.f;
    }

    #pragma unroll
    for (int tt = 0; tt < NTILE; ++tt) {
        const int col = tt * 16 + lane15;
        const bool isU = (tt < 10);                  // compile-time per tile
        const int ccol = isU ? col : col - HSTR;
        const float addB = isU ? b1p[ccol] : 0.f;
        const float addC = isU ? wci[ccol] : wcj[ccol];
        uint16_t* __restrict__ tab = isU ? u : v;
        #pragma unroll
        for (int j = 0; j < 4; ++j) {
            const int n = nbase + hi * 4 + j;
            if (n < nNodes)
                tab[(size_t)n * HSTR + ccol] = f2bf(acc[tt][j] + fmaf(cz[j], addC, addB));
        }
    }
}

// ---------------------------------------------------------------------------
// edge_kernel: 4 lanes per edge, 16 edges per wave.
//   lane r of each group loads chunks {r, 4+r, 8+r, 12+r, 16+r} (16 B each)
//   of u'[src] and v'[dst]; per-lane W2 slice in registers; 2-shuffle reduce.
// ---------------------------------------------------------------------------
__global__ void __launch_bounds__(256)
edge_kernel(const void* __restrict__ eiv,
            const uint16_t* __restrict__ u, const uint16_t* __restrict__ v,
            const float* __restrict__ w2p, const float* __restrict__ b2,
            const int* __restrict__ flag, float* __restrict__ out, int E)
{
    const int t = threadIdx.x;
    const int lane = t & 63;
    const int r = lane & 3;                 // chunk lane within 4-lane group
    const int grp = lane >> 2;              // 0..15: edge group within wave
    const int wid = blockIdx.x * (blockDim.x >> 6) + (t >> 6);
    const int eg = wid * 16 + grp;
    const bool ok = eg < E;
    const int e = ok ? eg : 0;
    const int is64 = *flag;
    const float bias2 = *b2;

    // per-lane W2 slice: chunk c = 4i+r covers elems 8c..8c+7
    const float4* w2f4 = (const float4*)w2p;
    float4 W2a[5], W2b[5];
    #pragma unroll
    for (int i = 0; i < 5; ++i) {
        const int c = 4 * i + r;
        W2a[i] = w2f4[2 * c];
        W2b[i] = w2f4[2 * c + 1];
    }

    int src, dst;
    if (is64) {
        const long long* e64 = (const long long*)eiv;
        src = (int)e64[e]; dst = (int)e64[(size_t)E + e];
    } else {
        const int* e32 = (const int*)eiv;
        src = e32[e];     dst = e32[(size_t)E + e];
    }

    const char* ub = (const char*)u + (uint32_t)src * 320u + r * 16;
    const char* vb = (const char*)v + (uint32_t)dst * 320u + r * 16;
    uint4 U[5], V[5];
    #pragma unroll
    for (int i = 0; i < 5; ++i) U[i] = *(const uint4*)(ub + 64 * i);
    #pragma unroll
    for (int i = 0; i < 5; ++i) V[i] = *(const uint4*)(vb + 64 * i);

    float acc0 = 0.f, acc1 = 0.f;
    #pragma unroll
    for (int i = 0; i < 5; ++i) {
        const uint32_t* uw = (const uint32_t*)&U[i];
        const uint32_t* vw = (const uint32_t*)&V[i];
        const float* wA = (const float*)&W2a[i];
        const float* wB = (const float*)&W2b[i];
        #pragma unroll
        for (int p = 0; p < 4; ++p) {
            const float ulo = __uint_as_float(uw[p] << 16);
            const float uhi = __uint_as_float(uw[p] & 0xFFFF0000u);
            const float vlo = __uint_as_float(vw[p] << 16);
            const float vhi = __uint_as_float(vw[p] & 0xFFFF0000u);
            const float t0 = fmaxf(ulo + vlo, 0.f);
            const float t1 = fmaxf(uhi + vhi, 0.f);
            const float wp0 = (p < 2) ? wA[2 * p]     : wB[2 * (p - 2)];
            const float wp1 = (p < 2) ? wA[2 * p + 1] : wB[2 * (p - 2) + 1];
            acc0 = fmaf(t0, wp0, acc0);
            acc1 = fmaf(t1, wp1, acc1);
        }
    }
    float partial = acc0 + acc1;
    partial += __shfl_xor(partial, 1);
    partial += __shfl_xor(partial, 2);
    if (r == 0 && ok)
        out[e] = 1.f / (1.f + __expf(-(partial + bias2)));
}

// ---------------------------------------------------------------------------
// fallback_kernel: direct per-edge compute (only if workspace too small)
// ---------------------------------------------------------------------------
__global__ void __launch_bounds__(256)
fallback_kernel(const void* __restrict__ eiv, const float* __restrict__ h,
                const float* __restrict__ cancer, const float* __restrict__ causal,
                const float* __restrict__ W1, const float* __restrict__ b1,
                const float* __restrict__ W2, const float* __restrict__ b2,
                float* __restrict__ out, int E)
{
    const int lane = threadIdx.x & 63;
    const int wpb  = blockDim.x >> 6;
    const int wid  = blockIdx.x * wpb + (threadIdx.x >> 6);
    const int nW   = gridDim.x * wpb;
    const uint32_t* p32 = (const uint32_t*)eiv;
    const uint32_t o = p32[1] | p32[3] | p32[5] | p32[7] | p32[9] | p32[11] | p32[13] | p32[15];
    const int is64 = (o == 0u);
    const long long* e64 = (const long long*)eiv;
    const int*       e32 = (const int*)eiv;
    const float bias2 = *b2;

    for (int e = wid; e < E; e += nW) {
        int src, dst;
        if (is64) { src = (int)e64[e]; dst = (int)e64[(size_t)E + e]; }
        else      { src = e32[e];      dst = e32[(size_t)E + e]; }
        const float ci = causal[src], cj = causal[dst];
        float acc0 = 0.f, acc1 = 0.f, acc2 = 0.f;
        const int j0 = lane, j1 = lane + 64, j2 = lane + 128;
        for (int k = 0; k < 291; ++k) {
            float f;
            if      (k < 128) f = h[(size_t)src * 128 + k];
            else if (k < 256) f = h[(size_t)dst * 128 + (k - 128)];
            else if (k < 288) f = cancer[k - 256];
            else if (k == 288) f = ci;
            else if (k == 289) f = cj;
            else               f = ci - cj;
            const float* wr = W1 + (size_t)k * HID;
            acc0 = fmaf(f, wr[j0], acc0);
            acc1 = fmaf(f, wr[j1], acc1);
            if (j2 < HID) acc2 = fmaf(f, wr[j2], acc2);
        }
        float partial = fmaxf(acc0 + b1[j0], 0.f) * W2[j0]
                      + fmaxf(acc1 + b1[j1], 0.f) * W2[j1];
        if (j2 < HID) partial += fmaxf(acc2 + b1[j2], 0.f) * W2[j2];
        #pragma unroll
        for (int m = 32; m; m >>= 1) partial += __shfl_xor(partial, m, 64);
        if (lane == 0) out[e] = 1.f / (1.f + __expf(-(partial + bias2)));
    }
}

// ---------------------------------------------------------------------------
extern "C" void kernel_launch(void* const* d_in, const int* in_sizes, int n_in,
                              void* d_out, int out_size, void* d_ws, size_t ws_size,
                              hipStream_t stream)
{
    const float* h      = (const float*)d_in[0];
    const void*  ei     = d_in[1];
    const float* cancer = (const float*)d_in[2];
    const float* causal = (const float*)d_in[3];
    const float* W1     = (const float*)d_in[4];
    const float* b1     = (const float*)d_in[5];
    const float* W2     = (const float*)d_in[6];
    const float* b2     = (const float*)d_in[7];
    float* outp = (float*)d_out;

    const int nNodes = in_sizes[0] / EMBED;
    const int E      = in_sizes[1] / 2;

    const size_t WPB_OFF = 8192;                                   // 81920 B, ends 90112
    const size_t U_OFF   = 98304;
    const size_t tabB    = (size_t)nNodes * HSTR * sizeof(uint16_t); // 16 MB
    const size_t V_OFF   = (U_OFF + tabB + 255) & ~(size_t)255;
    const size_t need    = V_OFF + tabB;

    if (ws_size >= need) {
        char* ws = (char*)d_ws;
        int*      flag = (int*)ws;
        float*    b1p  = (float*)(ws + 1024);
        float*    wci  = (float*)(ws + 2048);
        float*    wcj  = (float*)(ws + 3072);
        float*    w2p  = (float*)(ws + 4096);
        short*    Wpb  = (short*)(ws + WPB_OFF);
        uint16_t* u    = (uint16_t*)(ws + U_OFF);
        uint16_t* v    = (uint16_t*)(ws + V_OFF);

        prep_small<<<1, 256, 0, stream>>>(cancer, W1, b1, W2, ei, flag, b1p, wci, wcj, w2p);
        prep_packb<<<(KCH * NTILE * 64 * 8) / 256, 256, 0, stream>>>(W1, Wpb);
        proj_mfma<<<(nNodes + 63) / 64, 256, 0, stream>>>(h, Wpb, causal, b1p, wci, wcj,
                                                          u, v, nNodes);
        const int waves  = (E + 15) / 16;
        const int blocks = (waves + 3) / 4;
        edge_kernel<<<blocks, 256, 0, stream>>>(ei, u, v, w2p, b2, flag, outp, E);
    } else {
        fallback_kernel<<<2048, 256, 0, stream>>>(ei, h, cancer, causal, W1, b1, W2, b2,
                                                  outp, E);
    }
}